// Round 8
// baseline (112.550 us; speedup 1.0000x reference)
//
#include <hip/hip_runtime.h>
#include <cstdint>
#include <cmath>

#define NN   4096
#define DXX  128
#define DD   64
#define KK   256
#define HH   256
#define DIN  192   // DD + DXX
#define ROWS 8
#define NT   512
#define GRID (NN/ROWS)   // 512 blocks

// ---------------- Threefry-2x32 (20 rounds), exact JAX semantics ----------------
__device__ __forceinline__ uint32_t rotl32(uint32_t v, uint32_t r){ return (v<<r)|(v>>(32u-r)); }

__device__ __forceinline__ void tf2x32(uint32_t k0, uint32_t k1,
                                       uint32_t x0, uint32_t x1,
                                       uint32_t& o0, uint32_t& o1){
  const uint32_t ks0=k0, ks1=k1, ks2 = k0 ^ k1 ^ 0x1BD11BDAu;
  x0 += ks0; x1 += ks1;
  x0+=x1; x1=rotl32(x1,13); x1^=x0;
  x0+=x1; x1=rotl32(x1,15); x1^=x0;
  x0+=x1; x1=rotl32(x1,26); x1^=x0;
  x0+=x1; x1=rotl32(x1, 6); x1^=x0;
  x0+=ks1; x1+=ks2+1u;
  x0+=x1; x1=rotl32(x1,17); x1^=x0;
  x0+=x1; x1=rotl32(x1,29); x1^=x0;
  x0+=x1; x1=rotl32(x1,16); x1^=x0;
  x0+=x1; x1=rotl32(x1,24); x1^=x0;
  x0+=ks2; x1+=ks0+2u;
  x0+=x1; x1=rotl32(x1,13); x1^=x0;
  x0+=x1; x1=rotl32(x1,15); x1^=x0;
  x0+=x1; x1=rotl32(x1,26); x1^=x0;
  x0+=x1; x1=rotl32(x1, 6); x1^=x0;
  x0+=ks0; x1+=ks1+3u;
  x0+=x1; x1=rotl32(x1,17); x1^=x0;
  x0+=x1; x1=rotl32(x1,29); x1^=x0;
  x0+=x1; x1=rotl32(x1,16); x1^=x0;
  x0+=x1; x1=rotl32(x1,24); x1^=x0;
  x0+=ks1; x1+=ks2+4u;
  x0+=x1; x1=rotl32(x1,13); x1^=x0;
  x0+=x1; x1=rotl32(x1,15); x1^=x0;
  x0+=x1; x1=rotl32(x1,26); x1^=x0;
  x0+=x1; x1=rotl32(x1, 6); x1^=x0;
  x0+=ks2; x1+=ks0+5u;
  o0=x0; o1=x1;
}

__device__ __forceinline__ float gumbel_of(uint32_t ka0, uint32_t ka1, uint32_t idx){
  uint32_t o0,o1; tf2x32(ka0,ka1,0u,idx,o0,o1);
  const uint32_t bits = o0 ^ o1;
  const float TINY = 1.17549435e-38f;
  const float f = __uint_as_float((bits>>9) | 0x3F800000u) - 1.0f;
  const float u = fmaxf(TINY, f + TINY);
  return -logf(-logf(u));
}

// LDS overlay: [0,6144) in_s | [6144,14336) row | sdist overlays [0,8192)
// (row/in_s dead after MLP3) | [14336,30976) stg
__global__ __launch_bounds__(NT,4) void k_fused(
    const float* __restrict__ z, const float* __restrict__ ks,
    const float* __restrict__ xt, const void* __restrict__ maskp,
    const float* __restrict__ tr, const float* __restrict__ spk,
    const float* __restrict__ W1, const float* __restrict__ b1,
    const float* __restrict__ W2, const float* __restrict__ b2,
    const float* __restrict__ W3, const float* __restrict__ b3,
    const float* __restrict__ Cg, const int* __restrict__ seedp,
    float* __restrict__ out_z, float* __restrict__ out_kl,
    float* __restrict__ out_dkl, float* __restrict__ out_qk,
    int reps)
{
  const int t    = threadIdx.x;
  const int lane = t & 63;
  const int wv   = t >> 6;          // wave 0..7
  const int col  = t & 255;         // MLP1/2 output column
  const int rh   = t >> 8;          // row half (0/1)
  const int r0   = rh * 4;
  const int n0   = blockIdx.x * ROWS;
  const int nw   = n0 + wv;         // finalize: wave wv owns row nw

  __shared__ __align__(16) char smem[30976];
  float (*in_s)[DIN] = (float(*)[DIN]) smem;
  float (*row )[HH]  = (float(*)[HH]) (smem + 6144);
  float (*sdist)[KK] = (float(*)[KK]) smem;
  float (*stg )[65]  = (float(*)[65]) (smem + 14336);
  __shared__ __align__(16) float sgt[ROWS][DD];
  __shared__ int sh_flag;

  // ---- prefetch this wave's k_sample row (latency hidden under MLP) ----
  const float4 ksq = ((const float4*)ks)[(size_t)nw*(KK/4) + lane];

  // ---- mask dtype autodetect ----
  if (t==0) sh_flag = 0;
  __syncthreads();
  {
    const uint32_t* mw = (const uint32_t*)maskp;
    uint32_t bad=0;
    #pragma unroll
    for (int q=0;q<2;++q){ uint32_t wd=mw[t+q*NT]; if (wd!=0u && wd!=1u && wd!=0x3F800000u) bad=1; }
    if (bad) atomicOr(&sh_flag,1);
  }

  // ---- MLP input staging ----
  for (int i=t; i<ROWS*DIN; i+=NT){
    int r=i/DIN, d=i%DIN; int n=n0+r; float v;
    if (d<DD){ v = z[(size_t)n*DD+d]; if(!isfinite(v)) v=0.f; }
    else     { v = xt[(size_t)n*DXX + (d-DD)]; }
    in_s[r][d] = v;
  }
  __syncthreads();

  // ===== MEASUREMENT: run the full MLP stack `reps` times (idempotent) =====
  #pragma unroll 1
  for (int rep=0; rep<reps; ++rep){
    const int c3 = t & 63, rr = t >> 6;
    float a0,a1,a2,a3;
    // ---- MLP1: tanh([z,x]@W1+b1) -> row ----
    {
      const float bb = b1[col];
      a0=bb; a1=bb; a2=bb; a3=bb;
      float w0=W1[0*HH+col], w1=W1[1*HH+col], w2=W1[2*HH+col], w3=W1[3*HH+col];
      int d4=0;
      for (;;){
        const bool last = (d4+4>=DIN);
        float nw0,nw1,nw2,nw3;
        if (!last){
          nw0=W1[(d4+4)*HH+col]; nw1=W1[(d4+5)*HH+col];
          nw2=W1[(d4+6)*HH+col]; nw3=W1[(d4+7)*HH+col];
        }
        float4 x0=*(const float4*)&in_s[r0+0][d4];
        float4 x1=*(const float4*)&in_s[r0+1][d4];
        float4 x2=*(const float4*)&in_s[r0+2][d4];
        float4 x3=*(const float4*)&in_s[r0+3][d4];
        a0+=x0.x*w0; a0+=x0.y*w1; a0+=x0.z*w2; a0+=x0.w*w3;
        a1+=x1.x*w0; a1+=x1.y*w1; a1+=x1.z*w2; a1+=x1.w*w3;
        a2+=x2.x*w0; a2+=x2.y*w1; a2+=x2.z*w2; a2+=x2.w*w3;
        a3+=x3.x*w0; a3+=x3.y*w1; a3+=x3.z*w2; a3+=x3.w*w3;
        if (last) break;
        d4+=4; w0=nw0; w1=nw1; w2=nw2; w3=nw3;
      }
      row[r0+0][col]=tanhf(a0); row[r0+1][col]=tanhf(a1);
      row[r0+2][col]=tanhf(a2); row[r0+3][col]=tanhf(a3);
    }
    __syncthreads();
    // ---- MLP2: tanh(h1@W2+b2) -> row (in-place) ----
    {
      const float bb = b2[col];
      a0=bb; a1=bb; a2=bb; a3=bb;
      float w0=W2[0*HH+col], w1=W2[1*HH+col], w2=W2[2*HH+col], w3=W2[3*HH+col];
      int d4=0;
      for (;;){
        const bool last = (d4+4>=HH);
        float nw0,nw1,nw2,nw3;
        if (!last){
          nw0=W2[(d4+4)*HH+col]; nw1=W2[(d4+5)*HH+col];
          nw2=W2[(d4+6)*HH+col]; nw3=W2[(d4+7)*HH+col];
        }
        float4 x0=*(const float4*)&row[r0+0][d4];
        float4 x1=*(const float4*)&row[r0+1][d4];
        float4 x2=*(const float4*)&row[r0+2][d4];
        float4 x3=*(const float4*)&row[r0+3][d4];
        a0+=x0.x*w0; a0+=x0.y*w1; a0+=x0.z*w2; a0+=x0.w*w3;
        a1+=x1.x*w0; a1+=x1.y*w1; a1+=x1.z*w2; a1+=x1.w*w3;
        a2+=x2.x*w0; a2+=x2.y*w1; a2+=x2.z*w2; a2+=x2.w*w3;
        a3+=x3.x*w0; a3+=x3.y*w1; a3+=x3.z*w2; a3+=x3.w*w3;
        if (last) break;
        d4+=4; w0=nw0; w1=nw1; w2=nw2; w3=nw3;
      }
      __syncthreads();
      row[r0+0][col]=tanhf(a0); row[r0+1][col]=tanhf(a1);
      row[r0+2][col]=tanhf(a2); row[r0+3][col]=tanhf(a3);
    }
    __syncthreads();
    // ---- MLP3: gt = h2@W3+b3 -> sgt ----
    {
      float a = b3[c3];
      float w0=W3[0*DD+c3], w1=W3[1*DD+c3], w2=W3[2*DD+c3], w3=W3[3*DD+c3];
      int dp=0;
      for (;;){
        const bool last = (dp+4>=HH);
        float nw0,nw1,nw2,nw3;
        if (!last){
          nw0=W3[(dp+4)*DD+c3]; nw1=W3[(dp+5)*DD+c3];
          nw2=W3[(dp+6)*DD+c3]; nw3=W3[(dp+7)*DD+c3];
        }
        float4 h=*(const float4*)&row[rr][dp];
        a+=h.x*w0; a+=h.y*w1; a+=h.z*w2; a+=h.w*w3;
        if (last) break;
        dp+=4; w0=nw0; w1=nw1; w2=nw2; w3=nw3;
      }
      sgt[rr][c3] = a;
    }
    __syncthreads();   // sgt published; row safe to overwrite next rep
  }

  // ---- codebook -> registers (coalesced, LDS transpose, 4 chunks) ----
  float creg[DD];
  #pragma unroll 1
  for (int c=0;c<4;++c){
    __syncthreads();
    #pragma unroll
    for (int q=0;q<2;++q){
      int f=q*NT+t;
      float4 v=((const float4*)Cg)[c*1024+f];
      int cl=f>>4, d0=(f&15)*4;
      stg[cl][d0+0]=v.x; stg[cl][d0+1]=v.y; stg[cl][d0+2]=v.z; stg[cl][d0+3]=v.w;
    }
    __syncthreads();
    if ((t>>7)==c || ( (t>>6)&3 )==c){ }  // (no-op; ownership below)
    if (((t&255)>>6)==c && true){
      // threads whose col-quadrant matches chunk c load creg (both rh halves
      // must load the same codes as R5: thread t owns code (t&255)? No ——
      // R5 ownership: wave-of-256 split. Keep original: t owns code t for t<256
    }
    if ((t>>6)==c){            // original R5 ownership: waves 0..3 (t<256) codes
      #pragma unroll
      for (int d=0;d<DD;++d) creg[d]=stg[lane][d];
    } else if (((t-256)>>6)==c && t>=256){   // waves 4..7 duplicate codes 0..255
      #pragma unroll
      for (int d=0;d<DD;++d) creg[d]=stg[lane][d];
    }
  }
  __syncthreads();

  // ---- distance partials: thread (col,rh) does half the d-range for all rows ----
  float* sp = (float*)smem;          // overlay (in_s/row dead)
  #pragma unroll 1
  for (int r=0;r<ROWS;++r){
    float p=0.f;
    #pragma unroll
    for (int d4=0; d4<32; d4+=4){
      float4 s4 = *(const float4*)&sgt[r][rh*32+d4];
      float df;
      df=s4.x-creg[rh*32+d4+0]; p+=df*df;
      df=s4.y-creg[rh*32+d4+1]; p+=df*df;
      df=s4.z-creg[rh*32+d4+2]; p+=df*df;
      df=s4.w-creg[rh*32+d4+3]; p+=df*df;
    }
    sp[rh*2048 + r*256 + col] = p;
  }
  __syncthreads();

  // ---- wave-local finalize: wave wv owns row nw, no barriers ----
  const int flag = sh_flag;
  uint32_t ka0,ka1;
  tf2x32(0u,(uint32_t)seedp[0],0u,0u,ka0,ka1);   // partitionable split: k_rng

  // carry index (one-hot argmax)
  int kv=0x7fffffff;
  if (isfinite(ksq.x)&&ksq.x>0.5f) kv=4*lane+0;
  if (isfinite(ksq.y)&&ksq.y>0.5f&&4*lane+1<kv) kv=4*lane+1;
  if (isfinite(ksq.z)&&ksq.z>0.5f&&4*lane+2<kv) kv=4*lane+2;
  if (isfinite(ksq.w)&&ksq.w>0.5f&&4*lane+3<kv) kv=4*lane+3;
  { unsigned long long bl=__ballot(kv!=0x7fffffff);
    if (bl){ int src=(int)__builtin_ctzll(bl); kv=__shfl(kv,src,64); } else kv=0; }
  const int kidx = kv;
  const float4 trq=((const float4*)tr)[(size_t)nw*(KK*KK/4)+(size_t)kidx*(KK/4)+lane];

  // VQ argmin (first-index tie-break)
  float4 p0 = *(const float4*)&sp[       wv*256 + 4*lane];
  float4 p1 = *(const float4*)&sp[2048 + wv*256 + 4*lane];
  float dv = sqrtf(p0.x+p1.x); int di = 4*lane;
  { float d1=sqrtf(p0.y+p1.y); if(d1<dv){dv=d1;di=4*lane+1;}
    float d2=sqrtf(p0.z+p1.z); if(d2<dv){dv=d2;di=4*lane+2;}
    float d3=sqrtf(p0.w+p1.w); if(d3<dv){dv=d3;di=4*lane+3;} }
  #pragma unroll
  for (int m=32;m;m>>=1){
    float ov=__shfl_xor(dv,m,64); int oi=__shfl_xor(di,m,64);
    if (ov<dv||(ov==dv&&oi<di)){dv=ov;di=oi;}
  }
  const int qk=di;

  // prior normalization
  float s=((trq.x+trq.y)+trq.z)+trq.w;
  #pragma unroll
  for (int m=32;m;m>>=1) s+=__shfl_xor(s,m,64);
  float q0=trq.x/s, q1=trq.y/s, q2=trq.z/s, q3=trq.w/s;
  { bool f0=isfinite(ksq.x),f1=isfinite(ksq.y),f2=isfinite(ksq.z),f3=isfinite(ksq.w);
    if (__any(!(f0&&f1&&f2&&f3))){
      float4 sq=((const float4*)spk)[(size_t)nw*(KK/4)+lane];
      if(!f0)q0=sq.x; if(!f1)q1=sq.y; if(!f2)q2=sq.z; if(!f3)q3=sq.w;
    } }
  const float lp0=logf(q0), lp1=logf(q1), lp2=logf(q2), lp3=logf(q3);
  const int jq=qk&3;
  float lps=(jq==0)?lp0:((jq==1)?lp1:((jq==2)?lp2:lp3));
  const float logqk=__shfl(lps,qk>>2,64);

  // mask (uniform per row)
  bool m;
  if (flag) m=((const unsigned char*)maskp)[nw]!=0;
  else      m=((const uint32_t*)maskp)[nw]!=0u;

  int sel;
  if (m){ sel=qk; }
  else {
    float sc=gumbel_of(ka0,ka1,(uint32_t)(nw*KK+4*lane+0))+lp0; int si=4*lane;
    { float g=gumbel_of(ka0,ka1,(uint32_t)(nw*KK+4*lane+1))+lp1; if(g>sc){sc=g;si=4*lane+1;} }
    { float g=gumbel_of(ka0,ka1,(uint32_t)(nw*KK+4*lane+2))+lp2; if(g>sc){sc=g;si=4*lane+2;} }
    { float g=gumbel_of(ka0,ka1,(uint32_t)(nw*KK+4*lane+3))+lp3; if(g>sc){sc=g;si=4*lane+3;} }
    #pragma unroll
    for (int mm=32;mm;mm>>=1){
      float ov=__shfl_xor(sc,mm,64); int oi=__shfl_xor(si,mm,64);
      if (ov>sc||(ov==sc&&oi<si)){sc=ov;si=oi;}
    }
    sel=si;
  }

  ((float4*)out_qk)[(size_t)nw*(KK/4)+lane]=make_float4(
    (4*lane+0==qk)?1.f:0.f,(4*lane+1==qk)?1.f:0.f,
    (4*lane+2==qk)?1.f:0.f,(4*lane+3==qk)?1.f:0.f);

  const float c=Cg[(size_t)sel*DD+lane];
  out_z[(size_t)nw*DD+lane]=c;
  float df=sgt[wv][lane]-c;
  float p=df*df;
  #pragma unroll
  for (int mm=32;mm;mm>>=1) p+=__shfl_xor(p,mm,64);
  if (lane==0){
    float tt=sqrtf(p);
    float dkl=-logqk;
    out_kl[nw]=(tt+0.25f*tt)+dkl;
    out_dkl[nw]=dkl;
  }
}

extern "C" void kernel_launch(void* const* d_in, const int* in_sizes, int n_in,
                              void* d_out, int out_size, void* d_ws, size_t ws_size,
                              hipStream_t stream){
  const float* z    = (const float*)d_in[1];
  const float* ksm  = (const float*)d_in[2];
  const float* xt   = (const float*)d_in[3];
  const void*  mask = d_in[4];
  const float* tr   = (const float*)d_in[5];
  const float* spk  = (const float*)d_in[6];
  const float* W1   = (const float*)d_in[7];
  const float* b1   = (const float*)d_in[8];
  const float* W2   = (const float*)d_in[9];
  const float* b2   = (const float*)d_in[10];
  const float* W3   = (const float*)d_in[11];
  const float* b3   = (const float*)d_in[12];
  const float* C    = (const float*)d_in[13];
  const int*   seed = (const int*)d_in[14];

  float* out_z   = (float*)d_out;                // N*D
  float* out_kl  = out_z   + (size_t)NN*DD;      // N
  float* out_dkl = out_kl  + NN;                 // N
  float* out_qk  = out_dkl + NN;                 // N*K

  k_fused<<<GRID,NT,0,stream>>>(z, ksm, xt, mask, tr, spk,
                                W1, b1, W2, b2, W3, b3, C, seed,
                                out_z, out_kl, out_dkl, out_qk,
                                /*reps=*/2);
}

// Round 9
// 51.406 us; speedup vs baseline: 2.1894x; 2.1894x over previous
//
#include <hip/hip_runtime.h>
#include <cstdint>
#include <cmath>

#define NN   4096
#define DXX  128
#define DD   64
#define KK   256
#define HH   256
#define DIN  192   // DD + DXX
#define ROWS 8
#define NT   512
#define GRID (NN/ROWS)   // 512 blocks, 2 per CU (8 waves each -> 4 waves/SIMD)

// ---------------- Threefry-2x32 (20 rounds), exact JAX semantics ----------------
__device__ __forceinline__ uint32_t rotl32(uint32_t v, uint32_t r){ return (v<<r)|(v>>(32u-r)); }

__device__ __forceinline__ void tf2x32(uint32_t k0, uint32_t k1,
                                       uint32_t x0, uint32_t x1,
                                       uint32_t& o0, uint32_t& o1){
  const uint32_t ks0=k0, ks1=k1, ks2 = k0 ^ k1 ^ 0x1BD11BDAu;
  x0 += ks0; x1 += ks1;
  x0+=x1; x1=rotl32(x1,13); x1^=x0;
  x0+=x1; x1=rotl32(x1,15); x1^=x0;
  x0+=x1; x1=rotl32(x1,26); x1^=x0;
  x0+=x1; x1=rotl32(x1, 6); x1^=x0;
  x0+=ks1; x1+=ks2+1u;
  x0+=x1; x1=rotl32(x1,17); x1^=x0;
  x0+=x1; x1=rotl32(x1,29); x1^=x0;
  x0+=x1; x1=rotl32(x1,16); x1^=x0;
  x0+=x1; x1=rotl32(x1,24); x1^=x0;
  x0+=ks2; x1+=ks0+2u;
  x0+=x1; x1=rotl32(x1,13); x1^=x0;
  x0+=x1; x1=rotl32(x1,15); x1^=x0;
  x0+=x1; x1=rotl32(x1,26); x1^=x0;
  x0+=x1; x1=rotl32(x1, 6); x1^=x0;
  x0+=ks0; x1+=ks1+3u;
  x0+=x1; x1=rotl32(x1,17); x1^=x0;
  x0+=x1; x1=rotl32(x1,29); x1^=x0;
  x0+=x1; x1=rotl32(x1,16); x1^=x0;
  x0+=x1; x1=rotl32(x1,24); x1^=x0;
  x0+=ks1; x1+=ks2+4u;
  x0+=x1; x1=rotl32(x1,13); x1^=x0;
  x0+=x1; x1=rotl32(x1,15); x1^=x0;
  x0+=x1; x1=rotl32(x1,26); x1^=x0;
  x0+=x1; x1=rotl32(x1, 6); x1^=x0;
  x0+=ks2; x1+=ks0+5u;
  o0=x0; o1=x1;
}

__device__ __forceinline__ float gumbel_of(uint32_t ka0, uint32_t ka1, uint32_t idx){
  uint32_t o0,o1; tf2x32(ka0,ka1,0u,idx,o0,o1);
  const uint32_t bits = o0 ^ o1;
  const float TINY = 1.17549435e-38f;
  const float f = __uint_as_float((bits>>9) | 0x3F800000u) - 1.0f;
  const float u = fmaxf(TINY, f + TINY);
  return -logf(-logf(u));
}

// LDS overlay: [0,6144) in_s | [6144,14336) row | sp overlays [0,16384)
// (in_s/row dead after MLP3; tail of sp overlaps stg which is dead too) |
// [14336,30976) stg
__global__ __launch_bounds__(NT,4) void k_fused(
    const float* __restrict__ z, const float* __restrict__ ks,
    const float* __restrict__ xt, const void* __restrict__ maskp,
    const float* __restrict__ tr, const float* __restrict__ spk,
    const float* __restrict__ W1, const float* __restrict__ b1,
    const float* __restrict__ W2, const float* __restrict__ b2,
    const float* __restrict__ W3, const float* __restrict__ b3,
    const float* __restrict__ Cg, const int* __restrict__ seedp,
    float* __restrict__ out_z, float* __restrict__ out_kl,
    float* __restrict__ out_dkl, float* __restrict__ out_qk)
{
  const int t    = threadIdx.x;
  const int lane = t & 63;
  const int wv   = t >> 6;          // wave 0..7
  const int col  = t & 255;         // MLP1/2 output column
  const int rh   = t >> 8;          // row half (0/1)
  const int r0   = rh * 4;
  const int n0   = blockIdx.x * ROWS;
  const int nw   = n0 + wv;         // finalize: wave wv owns row nw

  __shared__ __align__(16) char smem[30976];
  float (*in_s)[DIN] = (float(*)[DIN]) smem;
  float (*row )[HH]  = (float(*)[HH]) (smem + 6144);
  float (*stg )[65]  = (float(*)[65]) (smem + 14336);
  float *sp          = (float*)smem;   // distance-partial overlay
  __shared__ __align__(16) float sgt[ROWS][DD];
  __shared__ int sh_flag;

  // ---- prefetch this wave's k_sample row (latency hidden under MLP) ----
  const float4 ksq = ((const float4*)ks)[(size_t)nw*(KK/4) + lane];

  // ---- mask dtype autodetect ----
  if (t==0) sh_flag = 0;
  __syncthreads();
  {
    const uint32_t* mw = (const uint32_t*)maskp;
    uint32_t bad=0;
    #pragma unroll
    for (int q=0;q<2;++q){ uint32_t wd=mw[t+q*NT]; if (wd!=0u && wd!=1u && wd!=0x3F800000u) bad=1; }
    if (bad) atomicOr(&sh_flag,1);
  }

  // ---- MLP input staging ----
  for (int i=t; i<ROWS*DIN; i+=NT){
    int r=i/DIN, d=i%DIN; int n=n0+r; float v;
    if (d<DD){ v = z[(size_t)n*DD+d]; if(!isfinite(v)) v=0.f; }
    else     { v = xt[(size_t)n*DXX + (d-DD)]; }
    in_s[r][d] = v;
  }
  __syncthreads();

  float acc0,acc1,acc2,acc3;
  float wA[16], wB[16];

  // ================= MLP1: tanh([z,x]@W1+b1), 12 K-tiles of 16, dbuf =========
  {
    const float bb = b1[col];
    acc0=bb; acc1=bb; acc2=bb; acc3=bb;
    const float* wp = W1 + col;
    #pragma unroll
    for (int i=0;i<16;++i) wA[i] = wp[(size_t)i*HH];
    #pragma unroll 1
    for (int tl=0; tl<12; tl+=2){
      #pragma unroll
      for (int i=0;i<16;++i) wB[i] = wp[(size_t)(tl*16+16+i)*HH];
      { const int k0 = tl*16;
        #pragma unroll
        for (int q=0;q<4;++q){
          float4 x0=*(const float4*)&in_s[r0+0][k0+4*q];
          float4 x1=*(const float4*)&in_s[r0+1][k0+4*q];
          float4 x2=*(const float4*)&in_s[r0+2][k0+4*q];
          float4 x3=*(const float4*)&in_s[r0+3][k0+4*q];
          acc0+=x0.x*wA[4*q+0]; acc0+=x0.y*wA[4*q+1]; acc0+=x0.z*wA[4*q+2]; acc0+=x0.w*wA[4*q+3];
          acc1+=x1.x*wA[4*q+0]; acc1+=x1.y*wA[4*q+1]; acc1+=x1.z*wA[4*q+2]; acc1+=x1.w*wA[4*q+3];
          acc2+=x2.x*wA[4*q+0]; acc2+=x2.y*wA[4*q+1]; acc2+=x2.z*wA[4*q+2]; acc2+=x2.w*wA[4*q+3];
          acc3+=x3.x*wA[4*q+0]; acc3+=x3.y*wA[4*q+1]; acc3+=x3.z*wA[4*q+2]; acc3+=x3.w*wA[4*q+3];
        } }
      if (tl+2<12){
        #pragma unroll
        for (int i=0;i<16;++i) wA[i] = wp[(size_t)(tl*16+32+i)*HH];
      }
      { const int k0 = tl*16+16;
        #pragma unroll
        for (int q=0;q<4;++q){
          float4 x0=*(const float4*)&in_s[r0+0][k0+4*q];
          float4 x1=*(const float4*)&in_s[r0+1][k0+4*q];
          float4 x2=*(const float4*)&in_s[r0+2][k0+4*q];
          float4 x3=*(const float4*)&in_s[r0+3][k0+4*q];
          acc0+=x0.x*wB[4*q+0]; acc0+=x0.y*wB[4*q+1]; acc0+=x0.z*wB[4*q+2]; acc0+=x0.w*wB[4*q+3];
          acc1+=x1.x*wB[4*q+0]; acc1+=x1.y*wB[4*q+1]; acc1+=x1.z*wB[4*q+2]; acc1+=x1.w*wB[4*q+3];
          acc2+=x2.x*wB[4*q+0]; acc2+=x2.y*wB[4*q+1]; acc2+=x2.z*wB[4*q+2]; acc2+=x2.w*wB[4*q+3];
          acc3+=x3.x*wB[4*q+0]; acc3+=x3.y*wB[4*q+1]; acc3+=x3.z*wB[4*q+2]; acc3+=x3.w*wB[4*q+3];
        } }
    }
    row[r0+0][col]=tanhf(acc0); row[r0+1][col]=tanhf(acc1);
    row[r0+2][col]=tanhf(acc2); row[r0+3][col]=tanhf(acc3);
  }
  __syncthreads();

  // ================= MLP2: tanh(h1@W2+b2), 16 K-tiles of 16, dbuf ============
  {
    const float bb = b2[col];
    acc0=bb; acc1=bb; acc2=bb; acc3=bb;
    const float* wp = W2 + col;
    #pragma unroll
    for (int i=0;i<16;++i) wA[i] = wp[(size_t)i*HH];
    #pragma unroll 1
    for (int tl=0; tl<16; tl+=2){
      #pragma unroll
      for (int i=0;i<16;++i) wB[i] = wp[(size_t)(tl*16+16+i)*HH];
      { const int k0 = tl*16;
        #pragma unroll
        for (int q=0;q<4;++q){
          float4 x0=*(const float4*)&row[r0+0][k0+4*q];
          float4 x1=*(const float4*)&row[r0+1][k0+4*q];
          float4 x2=*(const float4*)&row[r0+2][k0+4*q];
          float4 x3=*(const float4*)&row[r0+3][k0+4*q];
          acc0+=x0.x*wA[4*q+0]; acc0+=x0.y*wA[4*q+1]; acc0+=x0.z*wA[4*q+2]; acc0+=x0.w*wA[4*q+3];
          acc1+=x1.x*wA[4*q+0]; acc1+=x1.y*wA[4*q+1]; acc1+=x1.z*wA[4*q+2]; acc1+=x1.w*wA[4*q+3];
          acc2+=x2.x*wA[4*q+0]; acc2+=x2.y*wA[4*q+1]; acc2+=x2.z*wA[4*q+2]; acc2+=x2.w*wA[4*q+3];
          acc3+=x3.x*wA[4*q+0]; acc3+=x3.y*wA[4*q+1]; acc3+=x3.z*wA[4*q+2]; acc3+=x3.w*wA[4*q+3];
        } }
      if (tl+2<16){
        #pragma unroll
        for (int i=0;i<16;++i) wA[i] = wp[(size_t)(tl*16+32+i)*HH];
      }
      { const int k0 = tl*16+16;
        #pragma unroll
        for (int q=0;q<4;++q){
          float4 x0=*(const float4*)&row[r0+0][k0+4*q];
          float4 x1=*(const float4*)&row[r0+1][k0+4*q];
          float4 x2=*(const float4*)&row[r0+2][k0+4*q];
          float4 x3=*(const float4*)&row[r0+3][k0+4*q];
          acc0+=x0.x*wB[4*q+0]; acc0+=x0.y*wB[4*q+1]; acc0+=x0.z*wB[4*q+2]; acc0+=x0.w*wB[4*q+3];
          acc1+=x1.x*wB[4*q+0]; acc1+=x1.y*wB[4*q+1]; acc1+=x1.z*wB[4*q+2]; acc1+=x1.w*wB[4*q+3];
          acc2+=x2.x*wB[4*q+0]; acc2+=x2.y*wB[4*q+1]; acc2+=x2.z*wB[4*q+2]; acc2+=x2.w*wB[4*q+3];
          acc3+=x3.x*wB[4*q+0]; acc3+=x3.y*wB[4*q+1]; acc3+=x3.z*wB[4*q+2]; acc3+=x3.w*wB[4*q+3];
        } }
    }
    __syncthreads();   // all h1 reads complete before in-place overwrite
    row[r0+0][col]=tanhf(acc0); row[r0+1][col]=tanhf(acc1);
    row[r0+2][col]=tanhf(acc2); row[r0+3][col]=tanhf(acc3);
  }
  __syncthreads();

  // ================= MLP3: gt = h2@W3+b3, 16 K-tiles of 16, dbuf =============
  {
    const int c3 = t & 63, rr = t >> 6;
    float a = b3[c3];
    const float* wp = W3 + c3;
    #pragma unroll
    for (int i=0;i<16;++i) wA[i] = wp[(size_t)i*DD];
    #pragma unroll 1
    for (int tl=0; tl<16; tl+=2){
      #pragma unroll
      for (int i=0;i<16;++i) wB[i] = wp[(size_t)(tl*16+16+i)*DD];
      { const int k0 = tl*16;
        #pragma unroll
        for (int q=0;q<4;++q){
          float4 h=*(const float4*)&row[rr][k0+4*q];
          a+=h.x*wA[4*q+0]; a+=h.y*wA[4*q+1]; a+=h.z*wA[4*q+2]; a+=h.w*wA[4*q+3];
        } }
      if (tl+2<16){
        #pragma unroll
        for (int i=0;i<16;++i) wA[i] = wp[(size_t)(tl*16+32+i)*DD];
      }
      { const int k0 = tl*16+16;
        #pragma unroll
        for (int q=0;q<4;++q){
          float4 h=*(const float4*)&row[rr][k0+4*q];
          a+=h.x*wB[4*q+0]; a+=h.y*wB[4*q+1]; a+=h.z*wB[4*q+2]; a+=h.w*wB[4*q+3];
        } }
    }
    sgt[rr][c3] = a;
  }

  // ---- codebook -> registers: thread (col,rh) holds C[col][rh*32..rh*32+31] ----
  float creg[32];
  #pragma unroll 1
  for (int cc=0; cc<4; ++cc){
    __syncthreads();                 // protect stg reuse (and fences sgt on cc=0)
    #pragma unroll
    for (int q=0;q<2;++q){
      int f=q*NT+t;                  // float4 index within 64x64 chunk
      float4 v=((const float4*)Cg)[cc*1024+f];
      int cl=f>>4, d0=(f&15)*4;
      stg[cl][d0+0]=v.x; stg[cl][d0+1]=v.y; stg[cl][d0+2]=v.z; stg[cl][d0+3]=v.w;
    }
    __syncthreads();
    if ((col>>6)==cc){
      #pragma unroll
      for (int j=0;j<32;++j) creg[j]=stg[col&63][rh*32+j];
    }
  }
  __syncthreads();

  // ---- distance partials: thread (col,rh) does half the d-range for all rows ----
  #pragma unroll 1
  for (int r=0;r<ROWS;++r){
    float p=0.f;
    #pragma unroll
    for (int d4=0; d4<32; d4+=4){
      float4 s4 = *(const float4*)&sgt[r][rh*32+d4];
      float df;
      df=s4.x-creg[d4+0]; p+=df*df;
      df=s4.y-creg[d4+1]; p+=df*df;
      df=s4.z-creg[d4+2]; p+=df*df;
      df=s4.w-creg[d4+3]; p+=df*df;
    }
    sp[rh*2048 + r*256 + col] = p;
  }
  __syncthreads();

  // ---- wave-local finalize: wave wv owns row nw, no barriers ----
  const int flag = sh_flag;
  uint32_t ka0,ka1;
  tf2x32(0u,(uint32_t)seedp[0],0u,0u,ka0,ka1);   // partitionable split: k_rng

  // carry index (one-hot argmax)
  int kv=0x7fffffff;
  if (isfinite(ksq.x)&&ksq.x>0.5f) kv=4*lane+0;
  if (isfinite(ksq.y)&&ksq.y>0.5f&&4*lane+1<kv) kv=4*lane+1;
  if (isfinite(ksq.z)&&ksq.z>0.5f&&4*lane+2<kv) kv=4*lane+2;
  if (isfinite(ksq.w)&&ksq.w>0.5f&&4*lane+3<kv) kv=4*lane+3;
  { unsigned long long bl=__ballot(kv!=0x7fffffff);
    if (bl){ int src=(int)__builtin_ctzll(bl); kv=__shfl(kv,src,64); } else kv=0; }
  const int kidx = kv;
  const float4 trq=((const float4*)tr)[(size_t)nw*(KK*KK/4)+(size_t)kidx*(KK/4)+lane];

  // VQ argmin (first-index tie-break)
  float4 p0 = *(const float4*)&sp[       wv*256 + 4*lane];
  float4 p1 = *(const float4*)&sp[2048 + wv*256 + 4*lane];
  float dv = sqrtf(p0.x+p1.x); int di = 4*lane;
  { float d1=sqrtf(p0.y+p1.y); if(d1<dv){dv=d1;di=4*lane+1;}
    float d2=sqrtf(p0.z+p1.z); if(d2<dv){dv=d2;di=4*lane+2;}
    float d3=sqrtf(p0.w+p1.w); if(d3<dv){dv=d3;di=4*lane+3;} }
  #pragma unroll
  for (int m=32;m;m>>=1){
    float ov=__shfl_xor(dv,m,64); int oi=__shfl_xor(di,m,64);
    if (ov<dv||(ov==dv&&oi<di)){dv=ov;di=oi;}
  }
  const int qk=di;

  // prior normalization
  float s=((trq.x+trq.y)+trq.z)+trq.w;
  #pragma unroll
  for (int m=32;m;m>>=1) s+=__shfl_xor(s,m,64);
  float q0=trq.x/s, q1=trq.y/s, q2=trq.z/s, q3=trq.w/s;
  { bool f0=isfinite(ksq.x),f1=isfinite(ksq.y),f2=isfinite(ksq.z),f3=isfinite(ksq.w);
    if (__any(!(f0&&f1&&f2&&f3))){
      float4 sq=((const float4*)spk)[(size_t)nw*(KK/4)+lane];
      if(!f0)q0=sq.x; if(!f1)q1=sq.y; if(!f2)q2=sq.z; if(!f3)q3=sq.w;
    } }
  const float lp0=logf(q0), lp1=logf(q1), lp2=logf(q2), lp3=logf(q3);
  const int jq=qk&3;
  float lps=(jq==0)?lp0:((jq==1)?lp1:((jq==2)?lp2:lp3));
  const float logqk=__shfl(lps,qk>>2,64);

  // mask (uniform per row)
  bool m;
  if (flag) m=((const unsigned char*)maskp)[nw]!=0;
  else      m=((const uint32_t*)maskp)[nw]!=0u;

  int sel;
  if (m){ sel=qk; }
  else {
    float sc=gumbel_of(ka0,ka1,(uint32_t)(nw*KK+4*lane+0))+lp0; int si=4*lane;
    { float g=gumbel_of(ka0,ka1,(uint32_t)(nw*KK+4*lane+1))+lp1; if(g>sc){sc=g;si=4*lane+1;} }
    { float g=gumbel_of(ka0,ka1,(uint32_t)(nw*KK+4*lane+2))+lp2; if(g>sc){sc=g;si=4*lane+2;} }
    { float g=gumbel_of(ka0,ka1,(uint32_t)(nw*KK+4*lane+3))+lp3; if(g>sc){sc=g;si=4*lane+3;} }
    #pragma unroll
    for (int mm=32;mm;mm>>=1){
      float ov=__shfl_xor(sc,mm,64); int oi=__shfl_xor(si,mm,64);
      if (ov>sc||(ov==sc&&oi<si)){sc=ov;si=oi;}
    }
    sel=si;
  }

  ((float4*)out_qk)[(size_t)nw*(KK/4)+lane]=make_float4(
    (4*lane+0==qk)?1.f:0.f,(4*lane+1==qk)?1.f:0.f,
    (4*lane+2==qk)?1.f:0.f,(4*lane+3==qk)?1.f:0.f);

  const float c=Cg[(size_t)sel*DD+lane];
  out_z[(size_t)nw*DD+lane]=c;
  float df=sgt[wv][lane]-c;
  float p=df*df;
  #pragma unroll
  for (int mm=32;mm;mm>>=1) p+=__shfl_xor(p,mm,64);
  if (lane==0){
    float tt=sqrtf(p);
    float dkl=-logqk;
    out_kl[nw]=(tt+0.25f*tt)+dkl;
    out_dkl[nw]=dkl;
  }
}

extern "C" void kernel_launch(void* const* d_in, const int* in_sizes, int n_in,
                              void* d_out, int out_size, void* d_ws, size_t ws_size,
                              hipStream_t stream){
  const float* z    = (const float*)d_in[1];
  const float* ksm  = (const float*)d_in[2];
  const float* xt   = (const float*)d_in[3];
  const void*  mask = d_in[4];
  const float* tr   = (const float*)d_in[5];
  const float* spk  = (const float*)d_in[6];
  const float* W1   = (const float*)d_in[7];
  const float* b1   = (const float*)d_in[8];
  const float* W2   = (const float*)d_in[9];
  const float* b2   = (const float*)d_in[10];
  const float* W3   = (const float*)d_in[11];
  const float* b3   = (const float*)d_in[12];
  const float* C    = (const float*)d_in[13];
  const int*   seed = (const int*)d_in[14];

  float* out_z   = (float*)d_out;                // N*D
  float* out_kl  = out_z   + (size_t)NN*DD;      // N
  float* out_dkl = out_kl  + NN;                 // N
  float* out_qk  = out_dkl + NN;                 // N*K

  k_fused<<<GRID,NT,0,stream>>>(z, ksm, xt, mask, tr, spk,
                                W1, b1, W2, b2, W3, b3, C, seed,
                                out_z, out_kl, out_dkl, out_qk);
}